// Round 4
// baseline (75.453 us; speedup 1.0000x reference)
//
#include <hip/hip_runtime.h>
#include <cfloat>

// DistLoss: out = sum_m min_{s,n} ||surfaces[s,n,:] - targets[m,:]||^2
// surfaces: [4,4096,3] f32 (flat SN=16384 points), targets: [16384,3] f32.
//
// R4: back to LDS broadcast (R3's s_load idea lost: 2-SGPR-operand fma is
// illegal -> mov-inflation / latency-bound). R2 was LDS-pipe-bound
// (4 ds_read_b128 per 4 points fed only T=8 targets). T=16 doubles pairs
// per broadcast read -> LDS and VALU pipes balanced (~768 cyc each per
// CU-iter at 16 waves/CU).
//   d(m,p) = s2[p] + x[p]*(-2 tx[m]) + y[p]*(-2 ty[m]) + z[p]*(-2 tz[m])
// -> 3 fma/pair + min3 per 2 pairs = 1.5 VALU inst/pair.
//
//  k1: grid (4,256), 256 thr, T=16 targets/thread, CHUNK=64 points.
//      Also zeroes the k2 election counter (block (0,0)).
//  k2: 256 blocks x 64 thr: min over 256 chunks per target, wave-sum ->
//      part[256]; last block (atomic election) reduces part -> out[0].
// Fixed reduction trees -> deterministic.

namespace {
constexpr int M   = 16384;   // targets
constexpr int SN  = 16384;   // 4 * 4096 surface points
constexpr int TPB = 256;
constexpr int T   = 16;                    // targets per thread
constexpr int TGT_PER_BLOCK = TPB * T;     // 4096
constexpr int NCHUNK = 256;
constexpr int CHUNK  = SN / NCHUNK;        // 64
constexpr int K2B = 256;                   // k2 blocks (M/64)
}

__global__ __launch_bounds__(TPB, 4) void dist_partial_min(
    const float* __restrict__ surf,   // [SN][3]
    const float* __restrict__ tgt,    // [M][3]
    float* __restrict__ wmin,         // [NCHUNK][M]
    unsigned* __restrict__ counter)   // election counter for k2
{
  __shared__ alignas(16) float4 spt[CHUNK];   // (x, y, z, s2)

  const int tid   = threadIdx.x;
  const int mbase = blockIdx.x * TGT_PER_BLOCK;
  const int cbase = blockIdx.y * CHUNK;

  if (blockIdx.x == 0 && blockIdx.y == 0 && tid == 0) counter[0] = 0u;

  if (tid < CHUNK) {
    const float* s = surf + (size_t)(cbase + tid) * 3;
    const float x = s[0], y = s[1], z = s[2];
    spt[tid] = make_float4(x, y, z, fmaf(x, x, fmaf(y, y, z * z)));
  }

  float tx[T], ty[T], tz[T], b2[T], mn[T];
#pragma unroll
  for (int j = 0; j < T; ++j) {
    const int m     = mbase + j * TPB + tid;
    const float* tp = tgt + (size_t)m * 3;
    const float a = tp[0], b = tp[1], c = tp[2];
    tx[j] = -2.0f * a; ty[j] = -2.0f * b; tz[j] = -2.0f * c;
    b2[j] = fmaf(a, a, fmaf(b, b, c * c));
    mn[j] = FLT_MAX;
  }
  __syncthreads();

  for (int p = 0; p < CHUNK; p += 4) {
    const float4 P0 = spt[p + 0];
    const float4 P1 = spt[p + 1];
    const float4 P2 = spt[p + 2];
    const float4 P3 = spt[p + 3];
#pragma unroll
    for (int j = 0; j < T; ++j) {
      const float d0 = fmaf(P0.x, tx[j], fmaf(P0.y, ty[j], fmaf(P0.z, tz[j], P0.w)));
      const float d1 = fmaf(P1.x, tx[j], fmaf(P1.y, ty[j], fmaf(P1.z, tz[j], P1.w)));
      const float d2 = fmaf(P2.x, tx[j], fmaf(P2.y, ty[j], fmaf(P2.z, tz[j], P2.w)));
      const float d3 = fmaf(P3.x, tx[j], fmaf(P3.y, ty[j], fmaf(P3.z, tz[j], P3.w)));
      mn[j] = fminf(fminf(mn[j], d0), d1);   // v_min3_f32
      mn[j] = fminf(fminf(mn[j], d2), d3);   // v_min3_f32
    }
  }

#pragma unroll
  for (int j = 0; j < T; ++j)
    wmin[(size_t)blockIdx.y * M + mbase + j * TPB + tid] = mn[j] + b2[j];
}

__global__ __launch_bounds__(64) void dist_min_sum(
    const float* __restrict__ wmin,   // [NCHUNK][M]
    float* __restrict__ part,         // [K2B]
    unsigned* __restrict__ counter,
    float* __restrict__ out)
{
  const int tid = threadIdx.x;
  const int m   = blockIdx.x * 64 + tid;

  float mnv = FLT_MAX;
  for (int c = 0; c < NCHUNK; ++c)
    mnv = fminf(mnv, wmin[(size_t)c * M + m]);

  float sum = mnv;
  for (int off = 32; off; off >>= 1) sum += __shfl_down(sum, off, 64);

  unsigned done = 0;
  if (tid == 0) {
    part[blockIdx.x] = sum;
    __threadfence();
    done = atomicAdd(counter, 1u);
  }
  done = __shfl(done, 0, 64);

  if (done == (unsigned)(K2B - 1)) {    // last block finalizes
    __threadfence();
    float v = 0.0f;
#pragma unroll
    for (int i = 0; i < K2B / 64; ++i) v += part[i * 64 + tid];
    for (int off = 32; off; off >>= 1) v += __shfl_down(v, off, 64);
    if (tid == 0) out[0] = v;
  }
}

extern "C" void kernel_launch(void* const* d_in, const int* in_sizes, int n_in,
                              void* d_out, int out_size, void* d_ws, size_t ws_size,
                              hipStream_t stream) {
  const float* surf = (const float*)d_in[0];   // 4*4096*3
  const float* tgt  = (const float*)d_in[1];   // 16384*3
  float* out = (float*)d_out;

  float*    wmin    = (float*)d_ws;                        // NCHUNK*M f32 = 16 MB
  float*    part    = wmin + (size_t)NCHUNK * M;           // K2B floats
  unsigned* counter = (unsigned*)(part + K2B);             // 1 u32

  dim3 g1(M / TGT_PER_BLOCK, NCHUNK);
  dist_partial_min<<<g1, TPB, 0, stream>>>(surf, tgt, wmin, counter);
  dist_min_sum<<<K2B, 64, 0, stream>>>(wmin, part, counter, out);
}

// Round 5
// 40.337 us; speedup vs baseline: 1.8706x; 1.8706x over previous
//
#include <hip/hip_runtime.h>
#include <cfloat>

// DistLoss: out = sum_m min_{s,n} ||surfaces[s,n,:] - targets[m,:]||^2
// surfaces: [4,4096,3] f32 (flat SN=16384), targets: [16384,3] f32.
//
// R5:
//  k1: expanded form d = s2 + x*(-2tx) + y*(-2ty) + z*(-2tz)  (+b2 post-min),
//      3 fma/pair + min3/2pairs. LDS broadcast of float4(x,y,z,s2), with a
//      REGISTER double-buffer (prefetch next 4 points before consuming the
//      current 4) to hide ds_read->use latency. T=8 targets/thread,
//      grid (8,128) = 1024 blocks = 4 waves/SIMD.
//  k2: min over 128 chunks per target with 4-way chunk split (256 blocks x
//      256 thr = 1024 waves, unroll 8 -> latency hidden), block-sum ->
//      part[256]; last block (atomic election) reduces part -> out[0].
// Fixed-order reduction trees -> deterministic.

namespace {
constexpr int M   = 16384;
constexpr int SN  = 16384;
constexpr int TPB = 256;
constexpr int T   = 8;                     // targets per thread
constexpr int TGT_PER_BLOCK = TPB * T;     // 2048
constexpr int NCHUNK = 128;
constexpr int CHUNK  = SN / NCHUNK;        // 128 points
constexpr int K2B    = 256;                // k2 blocks (64 targets each)
}

__global__ __launch_bounds__(TPB, 4) void dist_partial_min(
    const float* __restrict__ surf,   // [SN][3]
    const float* __restrict__ tgt,    // [M][3]
    float* __restrict__ wmin,         // [NCHUNK][M]
    unsigned* __restrict__ counter)   // k2 election counter (reset here)
{
  __shared__ alignas(16) float4 spt[CHUNK];   // (x, y, z, s2)

  const int tid   = threadIdx.x;
  const int mbase = blockIdx.x * TGT_PER_BLOCK;
  const int cbase = blockIdx.y * CHUNK;

  if (blockIdx.x == 0 && blockIdx.y == 0 && tid == 0) counter[0] = 0u;

  if (tid < CHUNK) {
    const float* s = surf + (size_t)(cbase + tid) * 3;
    const float x = s[0], y = s[1], z = s[2];
    spt[tid] = make_float4(x, y, z, fmaf(x, x, fmaf(y, y, z * z)));
  }

  float tx[T], ty[T], tz[T], b2[T], mn[T];
#pragma unroll
  for (int j = 0; j < T; ++j) {
    const int m     = mbase + j * TPB + tid;
    const float* tp = tgt + (size_t)m * 3;
    const float a = tp[0], b = tp[1], c = tp[2];
    tx[j] = -2.0f * a; ty[j] = -2.0f * b; tz[j] = -2.0f * c;
    b2[j] = fmaf(a, a, fmaf(b, b, c * c));
    mn[j] = FLT_MAX;
  }
  __syncthreads();

  // register double-buffer over LDS broadcasts
  float4 C0 = spt[0], C1 = spt[1], C2 = spt[2], C3 = spt[3];
  for (int p = 0; p < CHUNK; p += 4) {
    const int pn = (p + 4) & (CHUNK - 1);       // wraps on last iter (unused values)
    const float4 N0 = spt[pn + 0];
    const float4 N1 = spt[pn + 1];
    const float4 N2 = spt[pn + 2];
    const float4 N3 = spt[pn + 3];
#pragma unroll
    for (int j = 0; j < T; ++j) {
      const float d0 = fmaf(C0.x, tx[j], fmaf(C0.y, ty[j], fmaf(C0.z, tz[j], C0.w)));
      const float d1 = fmaf(C1.x, tx[j], fmaf(C1.y, ty[j], fmaf(C1.z, tz[j], C1.w)));
      const float d2 = fmaf(C2.x, tx[j], fmaf(C2.y, ty[j], fmaf(C2.z, tz[j], C2.w)));
      const float d3 = fmaf(C3.x, tx[j], fmaf(C3.y, ty[j], fmaf(C3.z, tz[j], C3.w)));
      mn[j] = fminf(fminf(mn[j], d0), d1);   // v_min3_f32
      mn[j] = fminf(fminf(mn[j], d2), d3);   // v_min3_f32
    }
    C0 = N0; C1 = N1; C2 = N2; C3 = N3;
  }

#pragma unroll
  for (int j = 0; j < T; ++j)
    wmin[(size_t)blockIdx.y * M + mbase + j * TPB + tid] = mn[j] + b2[j];
}

__global__ __launch_bounds__(256) void dist_min_sum(
    const float* __restrict__ wmin,   // [NCHUNK][M]
    float* __restrict__ part,         // [K2B]
    unsigned* __restrict__ counter,
    float* __restrict__ out)
{
  const int tid  = threadIdx.x;
  const int lane = tid & 63;
  const int w    = tid >> 6;                 // wave 0..3 -> chunk quarter
  const int m    = blockIdx.x * 64 + lane;

  float mnv = FLT_MAX;
  const int c0 = w * (NCHUNK / 4);
#pragma unroll 8
  for (int c = 0; c < NCHUNK / 4; ++c)
    mnv = fminf(mnv, wmin[(size_t)(c0 + c) * M + m]);

  __shared__ float red[4][64];
  red[w][lane] = mnv;
  __syncthreads();

  if (w == 0) {
    float v = fminf(fminf(red[0][lane], red[1][lane]),
                    fminf(red[2][lane], red[3][lane]));
    for (int off = 32; off; off >>= 1) v += __shfl_down(v, off, 64);

    unsigned done = 0;
    if (lane == 0) {
      part[blockIdx.x] = v;
      __threadfence();
      done = atomicAdd(counter, 1u);
    }
    done = __shfl(done, 0, 64);

    if (done == (unsigned)(K2B - 1)) {        // last block finalizes
      __threadfence();
      float s = 0.0f;
#pragma unroll
      for (int i = 0; i < K2B / 64; ++i) s += part[i * 64 + lane];
      for (int off = 32; off; off >>= 1) s += __shfl_down(s, off, 64);
      if (lane == 0) out[0] = s;
    }
  }
}

extern "C" void kernel_launch(void* const* d_in, const int* in_sizes, int n_in,
                              void* d_out, int out_size, void* d_ws, size_t ws_size,
                              hipStream_t stream) {
  const float* surf = (const float*)d_in[0];   // 4*4096*3
  const float* tgt  = (const float*)d_in[1];   // 16384*3
  float* out = (float*)d_out;

  float*    wmin    = (float*)d_ws;                        // NCHUNK*M f32 = 8 MB
  float*    part    = wmin + (size_t)NCHUNK * M;           // K2B floats
  unsigned* counter = (unsigned*)(part + K2B);             // 1 u32

  dim3 g1(M / TGT_PER_BLOCK, NCHUNK);
  dist_partial_min<<<g1, TPB, 0, stream>>>(surf, tgt, wmin, counter);
  dist_min_sum<<<K2B, 256, 0, stream>>>(wmin, part, counter, out);
}